// Round 6
// baseline (221.739 us; speedup 1.0000x reference)
//
#include <hip/hip_runtime.h>

// Problem constants (from reference setup_inputs)
constexpr int K    = 64;
constexpr int N    = 1024;
constexpr int DIN  = 16;
constexpr int H1   = 4;
constexpr int DOUT = 8;
constexpr int FC1  = 54;

#define ALPHA_F   (0.01f)
#define LOG2E_F   (1.4426950408889634f)

__device__ inline float fast_exp2(float x) {
#if __has_builtin(__builtin_amdgcn_exp2f)
    return __builtin_amdgcn_exp2f(x);      // raw v_exp_f32
#else
    return __expf(x * 0.6931471805599453f);
#endif
}

// ---------------------------------------------------------------------------
// prep kernel: three independent jobs split by blockIdx range.
//  A) blocks [0,2048):    maskT[jw*N+i] = ballot bits of adj[i][jw*64+lane]
//  B) blocks [2048,2112): LDS-tile transpose fc1_w [8192,54] -> wt [54,8192]
//  C) blocks [2112,2240): gat1 projection: h1 = X@W1; f11/f21 logits *log2e
// ---------------------------------------------------------------------------
__global__ __launch_bounds__(512) void prep_kernel(
        const int* __restrict__ adj, unsigned long long* __restrict__ maskT,
        const float* __restrict__ fc1w, float* __restrict__ wt,
        const float* __restrict__ X, const float* __restrict__ W1,
        const float* __restrict__ a1,
        float* __restrict__ h1, float* __restrict__ f11, float* __restrict__ f21) {
    int b = blockIdx.x;
    if (b < 2048) {
        int wave = threadIdx.x >> 6, lane = threadIdx.x & 63;
        int wid = b * 8 + wave;            // 0..16383
        int jw  = wid >> 10;               // 0..15
        int i   = wid & 1023;
        int v = adj[i * N + (jw << 6) + lane];        // coalesced 256B/wave
        unsigned long long m = __ballot(v > 0);       // bit lane = adj>0
        if (lane == 0) maskT[jw * N + i] = m;
    } else if (b < 2112) {
        // transpose 128-row tile: coalesced read + coalesced write via LDS
        __shared__ float tile[128 * FC1];
        const int m0 = (b - 2048) * 128;
        const float* src = fc1w + (size_t)m0 * FC1;
        for (int idx = threadIdx.x; idx < 128 * FC1; idx += 512)
            tile[idx] = src[idx];                     // consecutive
        __syncthreads();
        for (int idx = threadIdx.x; idx < 128 * FC1; idx += 512) {
            int c = idx >> 7, mm = idx & 127;
            wt[(size_t)c * (N * DOUT) + m0 + mm] = tile[mm * FC1 + c];
        }
    } else {
        int idx = (b - 2112) * 512 + threadIdx.x;     // < 65536 : k*N+n
        const float4* x4 = (const float4*)(X + (size_t)idx * DIN);
        float h[H1] = {0.f, 0.f, 0.f, 0.f};
        #pragma unroll
        for (int q = 0; q < 4; q++) {
            float4 xv = x4[q];
            #pragma unroll
            for (int f = 0; f < H1; f++) {
                h[f] += xv.x * W1[(q * 4 + 0) * H1 + f] + xv.y * W1[(q * 4 + 1) * H1 + f]
                      + xv.z * W1[(q * 4 + 2) * H1 + f] + xv.w * W1[(q * 4 + 3) * H1 + f];
            }
        }
        float s1 = 0.f, s2 = 0.f;
        #pragma unroll
        for (int f = 0; f < H1; f++) { s1 += h[f] * a1[f]; s2 += h[f] * a1[H1 + f]; }
        *(float4*)(h1 + (size_t)idx * H1) = make_float4(h[0], h[1], h[2], h[3]);
        f11[idx] = s1 * LOG2E_F;           // pre-scaled for exp2
        f21[idx] = s2 * LOG2E_F;
    }
}

// ---------------------------------------------------------------------------
// Attention v6: block = (k, iset of 256 rows, j-half of 512).  Grid = 512
// blocks x 512 thr -> 2 blocks/CU, 16 waves/CU (4/SIMD).  Stage h+f2 for the
// j-half in LDS (~18/10 KB); 8 waves each own a 64-j chunk (exactly one mask
// word per row); 4 rows per lane.  Raw partial (sum_p, sum_p*h) accumulated
// into a single [256][F+1] LDS buffer via ds atomics (stride F+1 is odd ->
// conflict-free), then dumped to a global slab; gat_comb merges the 2 halves.
// Softmax without max-subtract (logits pre-scaled by log2e -> raw exp2; mask
// zeroes p after exp -> exact).
// ---------------------------------------------------------------------------
template <int F>
__global__ __launch_bounds__(512, 4) void gat_attn6(
        const unsigned long long* __restrict__ maskT,  // [16][N]
        const float* __restrict__ h,    // [K,N,F]
        const float* __restrict__ f1,   // [K,N]  (x log2e)
        const float* __restrict__ f2,   // [K,N]  (x log2e)
        float* __restrict__ pslab) {    // [2][K*N][F+1]
    __shared__ float stage[512 * (F + 1)];     // h-half [512*F] + f2-half [512]
    __shared__ float part[256 * (F + 1)];
    float* h_lds  = stage;
    float* f2_lds = stage + 512 * F;

    const int tid  = threadIdx.x;
    const int wave = tid >> 6;
    const int lane = tid & 63;
    const int b    = blockIdx.x;
    const int jh   = b & 1;
    const int iset = (b >> 1) & 3;
    const int k    = b >> 3;
    const int ibase = iset * 256;
    const int jbase = jh * 512;

    // zero the partial buffer
    for (int idx = tid; idx < 256 * (F + 1); idx += 512) part[idx] = 0.f;

    // stage h[k][jbase..jbase+512][:] and f2[k][jbase..+512] (coalesced)
    {
        const float4* hg = (const float4*)(h + ((size_t)k * N + jbase) * F);
        #pragma unroll
        for (int m = tid; m < 512 * F / 4; m += 512)
            ((float4*)h_lds)[m] = hg[m];
        if (tid < 128)
            ((float4*)f2_lds)[tid] = ((const float4*)(f2 + k * N + jbase))[tid];
    }

    float f1r[4];
    #pragma unroll
    for (int r = 0; r < 4; r++) f1r[r] = f1[k * N + ibase + r * 64 + lane];

    // mask: this wave's 64-j chunk = word (jh*8 + wave) of each row
    unsigned long long mw[4];
    #pragma unroll
    for (int r = 0; r < 4; r++)
        mw[r] = maskT[(jh * 8 + wave) * N + ibase + r * 64 + lane];

    float s[4] = {0.f, 0.f, 0.f, 0.f};
    float acc[4][F];
    #pragma unroll
    for (int r = 0; r < 4; r++)
        #pragma unroll
        for (int f = 0; f < F; f++) acc[r][f] = 0.f;

    __syncthreads();

    const int lbase = wave * 64;               // local j base within the stage
    #pragma unroll
    for (int half = 0; half < 2; half++) {
        unsigned wb[4];
        #pragma unroll
        for (int r = 0; r < 4; r++)
            wb[r] = half ? (unsigned)(mw[r] >> 32) : (unsigned)mw[r];
        const int lj0 = lbase + half * 32;
        #pragma unroll 4
        for (int t = 0; t < 32; t++) {
            const int lj = lj0 + t;
            float f2j = f2_lds[lj];                          // broadcast
            float4 h0 = ((const float4*)h_lds)[lj * (F / 4)];
            float4 h1v;
            if (F == 8) h1v = ((const float4*)h_lds)[lj * 2 + 1];
            #pragma unroll
            for (int r = 0; r < 4; r++) {
                float x = f1r[r] + f2j;
                float e = fmaxf(x, ALPHA_F * x);
                float p = fast_exp2(e);
                p = (wb[r] & (1u << t)) ? p : 0.f;
                s[r] += p;
                acc[r][0] += p * h0.x; acc[r][1] += p * h0.y;
                acc[r][2] += p * h0.z; acc[r][3] += p * h0.w;
                if (F == 8) {
                    acc[r][4] += p * h1v.x; acc[r][5] += p * h1v.y;
                    acc[r][6] += p * h1v.z; acc[r][7] += p * h1v.w;
                }
            }
        }
    }

    // accumulate into the shared partial buffer (odd stride -> no conflicts)
    #pragma unroll
    for (int r = 0; r < 4; r++) {
        float* pp = part + (r * 64 + lane) * (F + 1);
        atomicAdd(pp, s[r]);
        #pragma unroll
        for (int f = 0; f < F; f++) atomicAdd(pp + 1 + f, acc[r][f]);
    }
    __syncthreads();

    // dump the 256-row partial chunk to the global slab (coalesced)
    float* dst = pslab + ((size_t)jh * K * N + (size_t)k * N + ibase) * (F + 1);
    for (int idx = tid; idx < 256 * (F + 1); idx += 512) dst[idx] = part[idx];
}

// ---------------------------------------------------------------------------
// Combine the two j-half partials: normalize, ReLU; FUSE applies the layer-2
// projection (W2, a2) producing h2/f12/f22, else writes the attention output.
// One thread per row (k*N+i).
// ---------------------------------------------------------------------------
template <int F, bool FUSE>
__global__ __launch_bounds__(256) void gat_comb(
        const float* __restrict__ pslab,   // [2][K*N][F+1]
        const float* __restrict__ W2, const float* __restrict__ a2,
        float* __restrict__ o_x, float* __restrict__ o_f1,
        float* __restrict__ o_f2) {
    const int row = blockIdx.x * 256 + threadIdx.x;   // 0..K*N-1
    const float* pa = pslab + (size_t)row * (F + 1);
    const float* pb = pslab + ((size_t)K * N + row) * (F + 1);
    float st = pa[0] + pb[0];
    float inv = (st > 0.f) ? 1.f / st : 0.f;
    float xo[F];
    #pragma unroll
    for (int f = 0; f < F; f++)
        xo[f] = fmaxf((pa[1 + f] + pb[1 + f]) * inv, 0.f);   // relu

    if constexpr (FUSE) {
        float hv[DOUT];
        #pragma unroll
        for (int f = 0; f < DOUT; f++) {
            hv[f] = xo[0] * W2[f]      + xo[1] * W2[8 + f]
                  + xo[2] * W2[16 + f] + xo[3] * W2[24 + f];
        }
        float t1 = 0.f, t2 = 0.f;
        #pragma unroll
        for (int f = 0; f < DOUT; f++) { t1 += hv[f] * a2[f]; t2 += hv[f] * a2[DOUT + f]; }
        float* op = o_x + (size_t)row * DOUT;
        *(float4*)op       = make_float4(hv[0], hv[1], hv[2], hv[3]);
        *(float4*)(op + 4) = make_float4(hv[4], hv[5], hv[6], hv[7]);
        o_f1[row] = t1 * LOG2E_F;
        o_f2[row] = t2 * LOG2E_F;
    } else {
        float* op = o_x + (size_t)row * F;
        *(float4*)op = make_float4(xo[0], xo[1], xo[2], xo[3]);
        if (F == 8)
            *(float4*)(op + 4) = make_float4(xo[4], xo[5], xo[6], xo[7]);
    }
}

// ---------------------------------------------------------------------------
// FC1: y[k,c] = relu( x2[k,:] . wt[c,:] + b[c] ).
// One 256-thread block per (k,c): 4 waves split the 8192-dim, 2 accumulator
// chains per wave, butterfly + LDS combine.
// ---------------------------------------------------------------------------
__global__ __launch_bounds__(256) void fc1_kernel(
        const float* __restrict__ x2, const float* __restrict__ wt,
        const float* __restrict__ b, float* __restrict__ y) {
    const int bid  = blockIdx.x;            // k*54 + c
    const int k    = bid / FC1;
    const int c    = bid - k * FC1;
    const int wave = threadIdx.x >> 6;
    const int lane = threadIdx.x & 63;
    const float4* x4 = (const float4*)(x2 + (size_t)k * N * DOUT) + wave * 512 + lane;
    const float4* w4 = (const float4*)(wt + (size_t)c * N * DOUT) + wave * 512 + lane;
    float s0 = 0.f, s1 = 0.f;
    #pragma unroll
    for (int q = 0; q < 8; q += 2) {
        float4 a0 = x4[q * 64],      w0 = w4[q * 64];
        float4 a1 = x4[q * 64 + 64], w1 = w4[q * 64 + 64];
        s0 += a0.x * w0.x + a0.y * w0.y + a0.z * w0.z + a0.w * w0.w;
        s1 += a1.x * w1.x + a1.y * w1.y + a1.z * w1.z + a1.w * w1.w;
    }
    float s = s0 + s1;
    #pragma unroll
    for (int off = 32; off > 0; off >>= 1) s += __shfl_xor(s, off);
    __shared__ float red[4];
    if (lane == 0) red[wave] = s;
    __syncthreads();
    if (threadIdx.x == 0)
        y[bid] = fmaxf(red[0] + red[1] + red[2] + red[3] + b[c], 0.f);
}

// ---------------------------------------------------------------------------
// Final: out[k,n] = y[k,:] . out_w[:,n] + out_b[n].  One thread per (k,n).
// ---------------------------------------------------------------------------
__global__ void fc2_kernel(const float* __restrict__ y,
                           const float* __restrict__ out_w,
                           const float* __restrict__ out_b,
                           float* __restrict__ out) {
    int n = blockIdx.x * blockDim.x + threadIdx.x;   // 0..1023
    int k = blockIdx.y;
    const float* yk = y + (size_t)k * FC1;
    float s = out_b[n];
    #pragma unroll 6
    for (int c = 0; c < FC1; c++) s += yk[c] * out_w[(size_t)c * N + n];
    out[(size_t)k * N + n] = s;
}

// ---------------------------------------------------------------------------
extern "C" void kernel_launch(void* const* d_in, const int* in_sizes, int n_in,
                              void* d_out, int out_size, void* d_ws, size_t ws_size,
                              hipStream_t stream) {
    const float* X     = (const float*)d_in[0];
    const int*   adj   = (const int*)  d_in[1];
    const float* W1    = (const float*)d_in[2];
    const float* a1    = (const float*)d_in[3];
    const float* W2    = (const float*)d_in[4];
    const float* a2    = (const float*)d_in[5];
    const float* fc1w  = (const float*)d_in[6];
    const float* fc1b  = (const float*)d_in[7];
    const float* outw  = (const float*)d_in[8];
    const float* outb  = (const float*)d_in[9];
    float* out = (float*)d_out;

    // Workspace layout (floats); ~13 MB total
    float* ws  = (float*)d_ws;
    float* h1  = ws;                       // 262144
    float* f11 = h1  + 262144;             // 65536
    float* f21 = f11 + 65536;              // 65536
    float* h2  = f21 + 65536;              // 524288
    float* f12 = h2  + 524288;             // 65536
    float* f22 = f12 + 65536;              // 65536
    float* x2  = f22 + 65536;              // 524288
    float* y   = x2  + 524288;             // 4096 (3456 used)
    float* wt  = y   + 4096;               // 442368
    float* ps  = wt  + 442368;             // 2*65536*9 = 1179648 (partial slab)
    unsigned long long* mT = (unsigned long long*)(ps + 1179648);  // 16384 u64

    // 1) fused prep: mask pack (transposed) + fc1_w transpose + gat1 proj
    prep_kernel<<<dim3(2240), dim3(512), 0, stream>>>(
        adj, mT, fc1w, wt, X, W1, a1, h1, f11, f21);

    // 2) layer-1 attention (j-split) + combine fused with layer-2 projection
    gat_attn6<4><<<dim3(512), dim3(512), 0, stream>>>(mT, h1, f11, f21, ps);
    gat_comb<4, true><<<dim3(K * N / 256), dim3(256), 0, stream>>>(
        ps, W2, a2, h2, f12, f22);

    // 3) layer-2 attention (j-split) + combine
    gat_attn6<8><<<dim3(512), dim3(512), 0, stream>>>(mT, h2, f12, f22, ps);
    gat_comb<8, false><<<dim3(K * N / 256), dim3(256), 0, stream>>>(
        ps, nullptr, nullptr, x2, nullptr, nullptr);

    // 4) FC head
    fc1_kernel<<<dim3(K * FC1), dim3(256), 0, stream>>>(x2, wt, fc1b, y);
    fc2_kernel<<<dim3(N / 256, K), dim3(256), 0, stream>>>(y, outw, outb, out);
}

// Round 7
// 163.356 us; speedup vs baseline: 1.3574x; 1.3574x over previous
//
#include <hip/hip_runtime.h>

// Problem constants (from reference setup_inputs)
constexpr int K    = 64;
constexpr int N    = 1024;
constexpr int DIN  = 16;
constexpr int H1   = 4;
constexpr int DOUT = 8;
constexpr int FC1  = 54;

#define ALPHA_F   (0.01f)
#define LOG2E_F   (1.4426950408889634f)

__device__ inline float fast_exp2(float x) {
#if __has_builtin(__builtin_amdgcn_exp2f)
    return __builtin_amdgcn_exp2f(x);      // raw v_exp_f32
#else
    return __expf(x * 0.6931471805599453f);
#endif
}

// ---------------------------------------------------------------------------
// prep kernel: three independent jobs split by blockIdx range.
//  A) blocks [0,2048):    maskT[jw*N+i] = ballot bits of adj[i][jw*64+lane]
//  B) blocks [2048,2112): LDS-tile transpose fc1_w [8192,54] -> wt [54,8192]
//  C) blocks [2112,2240): gat1 projection: h1 = X@W1; f11/f21 logits *log2e
// ---------------------------------------------------------------------------
__global__ __launch_bounds__(512) void prep_kernel(
        const int* __restrict__ adj, unsigned long long* __restrict__ maskT,
        const float* __restrict__ fc1w, float* __restrict__ wt,
        const float* __restrict__ X, const float* __restrict__ W1,
        const float* __restrict__ a1,
        float* __restrict__ h1, float* __restrict__ f11, float* __restrict__ f21) {
    int b = blockIdx.x;
    if (b < 2048) {
        int wave = threadIdx.x >> 6, lane = threadIdx.x & 63;
        int wid = b * 8 + wave;            // 0..16383
        int jw  = wid >> 10;               // 0..15
        int i   = wid & 1023;
        int v = adj[i * N + (jw << 6) + lane];        // coalesced 256B/wave
        unsigned long long m = __ballot(v > 0);       // bit lane = adj>0
        if (lane == 0) maskT[jw * N + i] = m;
    } else if (b < 2112) {
        // transpose 128-row tile: coalesced read + coalesced write via LDS
        __shared__ float tile[128 * FC1];
        const int m0 = (b - 2048) * 128;
        const float* src = fc1w + (size_t)m0 * FC1;
        for (int idx = threadIdx.x; idx < 128 * FC1; idx += 512)
            tile[idx] = src[idx];                     // consecutive
        __syncthreads();
        for (int idx = threadIdx.x; idx < 128 * FC1; idx += 512) {
            int c = idx >> 7, mm = idx & 127;
            wt[(size_t)c * (N * DOUT) + m0 + mm] = tile[mm * FC1 + c];
        }
    } else {
        int idx = (b - 2112) * 512 + threadIdx.x;     // < 65536 : k*N+n
        const float4* x4 = (const float4*)(X + (size_t)idx * DIN);
        float h[H1] = {0.f, 0.f, 0.f, 0.f};
        #pragma unroll
        for (int q = 0; q < 4; q++) {
            float4 xv = x4[q];
            #pragma unroll
            for (int f = 0; f < H1; f++) {
                h[f] += xv.x * W1[(q * 4 + 0) * H1 + f] + xv.y * W1[(q * 4 + 1) * H1 + f]
                      + xv.z * W1[(q * 4 + 2) * H1 + f] + xv.w * W1[(q * 4 + 3) * H1 + f];
            }
        }
        float s1 = 0.f, s2 = 0.f;
        #pragma unroll
        for (int f = 0; f < H1; f++) { s1 += h[f] * a1[f]; s2 += h[f] * a1[H1 + f]; }
        *(float4*)(h1 + (size_t)idx * H1) = make_float4(h[0], h[1], h[2], h[3]);
        f11[idx] = s1 * LOG2E_F;           // pre-scaled for exp2
        f21[idx] = s2 * LOG2E_F;
    }
}

// ---------------------------------------------------------------------------
// Attention v7: NO LDS staging — the per-j broadcast operands (f2[j], h[j])
// are read from GLOBAL with wave-uniform addresses (1 L1/L2 transaction,
// broadcast to all lanes; h[k]+f2[k] are L2-resident).  This moves the hot
// loop's operand traffic off the LDS pipe (which was serializing with VALU
// at 46% busy in v4/v5) onto the otherwise-idle VMEM/SMEM path.
// Shape: 512 thr (8 waves), 128 rows/block (2 rows per lane), j split 8-ways
// (128 j per wave = exactly 2 mask words), grid 512 -> 2 blocks/CU,
// 4 waves/SIMD.  LDS only for the [8][128][F+1] partials union (non-atomic,
// odd stride -> conflict-free).  Softmax without max-subtract (logits
// pre-scaled by log2e -> raw exp2; mask zeroes p after exp -> exact).
// FUSE: layer-2 projection (W2, a2) applied in the epilogue.
// ---------------------------------------------------------------------------
template <int F, bool FUSE>
__global__ __launch_bounds__(512, 4) void gat_attn7(
        const unsigned long long* __restrict__ maskT,  // [16][N]
        const float* __restrict__ h,    // [K,N,F]
        const float* __restrict__ f1,   // [K,N]  (x log2e)
        const float* __restrict__ f2,   // [K,N]  (x log2e)
        const float* __restrict__ W2,   // [4,8]  (FUSE only)
        const float* __restrict__ a2,   // [16]   (FUSE only)
        float* __restrict__ o_x,        // FUSE: h2 [K,N,8]; else out [K,N,F]
        float* __restrict__ o_f1,       // FUSE: f12 (x log2e)
        float* __restrict__ o_f2) {     // FUSE: f22 (x log2e)
    __shared__ float part[8 * 128 * (F + 1)];    // [wave][row][F+1]

    const int tid  = threadIdx.x;
    const int wave = tid >> 6;
    const int lane = tid & 63;
    const int k    = blockIdx.x >> 3;            // 8 blocks per k
    const int iset = blockIdx.x & 7;
    const int ibase = iset * 128;
    const int i0   = ibase + lane;
    const int i1   = i0 + 64;

    const float f1i0 = f1[k * N + i0];
    const float f1i1 = f1[k * N + i1];
    const float* f2k  = f2 + k * N;
    const float4* hk4 = (const float4*)(h + (size_t)k * N * F);

    float s0 = 0.f, s1 = 0.f;
    float acc0[F], acc1[F];
    #pragma unroll
    for (int f = 0; f < F; f++) { acc0[f] = 0.f; acc1[f] = 0.f; }

    const int j0 = wave * 128;                   // this wave's 128-j chunk
    #pragma unroll
    for (int w2 = 0; w2 < 2; w2++) {
        const int jbase = j0 + w2 * 64;
        const int mrow  = (jbase >> 6) * N;
        const unsigned long long mw0 = maskT[mrow + i0];   // coalesced
        const unsigned long long mw1 = maskT[mrow + i1];
        #pragma unroll
        for (int half = 0; half < 2; half++) {
            const unsigned wb0 = half ? (unsigned)(mw0 >> 32) : (unsigned)mw0;
            const unsigned wb1 = half ? (unsigned)(mw1 >> 32) : (unsigned)mw1;
            const int jb = jbase + half * 32;
            #pragma unroll 8
            for (int t = 0; t < 32; t++) {
                const int j = jb + t;
                float  f2j = f2k[j];                       // uniform -> bcast
                float4 h0  = hk4[j * (F / 4)];             // uniform -> bcast
                float4 h1v;
                if (F == 8) h1v = hk4[j * 2 + 1];
                // row 0
                {
                    float x = f1i0 + f2j;
                    float e = fmaxf(x, ALPHA_F * x);
                    float p = fast_exp2(e);
                    p = (wb0 & (1u << t)) ? p : 0.f;
                    s0 += p;
                    acc0[0] += p * h0.x; acc0[1] += p * h0.y;
                    acc0[2] += p * h0.z; acc0[3] += p * h0.w;
                    if (F == 8) {
                        acc0[4] += p * h1v.x; acc0[5] += p * h1v.y;
                        acc0[6] += p * h1v.z; acc0[7] += p * h1v.w;
                    }
                }
                // row 1
                {
                    float x = f1i1 + f2j;
                    float e = fmaxf(x, ALPHA_F * x);
                    float p = fast_exp2(e);
                    p = (wb1 & (1u << t)) ? p : 0.f;
                    s1 += p;
                    acc1[0] += p * h0.x; acc1[1] += p * h0.y;
                    acc1[2] += p * h0.z; acc1[3] += p * h0.w;
                    if (F == 8) {
                        acc1[4] += p * h1v.x; acc1[5] += p * h1v.y;
                        acc1[6] += p * h1v.z; acc1[7] += p * h1v.w;
                    }
                }
            }
        }
    }

    // write per-wave partials (stride F+1 odd -> conflict-free)
    {
        float* p0 = part + (wave * 128 + lane) * (F + 1);
        p0[0] = s0;
        #pragma unroll
        for (int f = 0; f < F; f++) p0[1 + f] = acc0[f];
        float* p1 = part + (wave * 128 + lane + 64) * (F + 1);
        p1[0] = s1;
        #pragma unroll
        for (int f = 0; f < F; f++) p1[1 + f] = acc1[f];
    }
    __syncthreads();

    if (tid < 128) {
        const int r = tid;
        float st = 0.f;
        float at[F];
        #pragma unroll
        for (int f = 0; f < F; f++) at[f] = 0.f;
        #pragma unroll
        for (int w = 0; w < 8; w++) {
            const float* pp = part + (w * 128 + r) * (F + 1);
            st += pp[0];
            #pragma unroll
            for (int f = 0; f < F; f++) at[f] += pp[1 + f];
        }
        const float inv = (st > 0.f) ? 1.f / st : 0.f;
        const int orow = k * N + ibase + r;
        float xo[F];
        #pragma unroll
        for (int f = 0; f < F; f++) xo[f] = fmaxf(at[f] * inv, 0.f);  // relu

        if constexpr (FUSE) {
            // layer-2 projection: h2 = xo(4) @ W2(4x8); logits vs a2 (x log2e)
            float hv[DOUT];
            #pragma unroll
            for (int f = 0; f < DOUT; f++) {
                hv[f] = xo[0] * W2[f]      + xo[1] * W2[8 + f]
                      + xo[2] * W2[16 + f] + xo[3] * W2[24 + f];
            }
            float t1 = 0.f, t2 = 0.f;
            #pragma unroll
            for (int f = 0; f < DOUT; f++) { t1 += hv[f] * a2[f]; t2 += hv[f] * a2[DOUT + f]; }
            float* op = o_x + (size_t)orow * DOUT;
            *(float4*)op       = make_float4(hv[0], hv[1], hv[2], hv[3]);
            *(float4*)(op + 4) = make_float4(hv[4], hv[5], hv[6], hv[7]);
            o_f1[orow] = t1 * LOG2E_F;
            o_f2[orow] = t2 * LOG2E_F;
        } else {
            float* op = o_x + (size_t)orow * F;
            *(float4*)op = make_float4(xo[0], xo[1], xo[2], xo[3]);
            if (F == 8)
                *(float4*)(op + 4) = make_float4(xo[4], xo[5], xo[6], xo[7]);
        }
    }
}

// ---------------------------------------------------------------------------
// FC1: y[k,c] = relu( x2[k,:] . wt[c,:] + b[c] ).
// One 256-thread block per (k,c): 4 waves split the 8192-dim, 2 accumulator
// chains per wave, butterfly + LDS combine.
// ---------------------------------------------------------------------------
__global__ __launch_bounds__(256) void fc1_kernel(
        const float* __restrict__ x2, const float* __restrict__ wt,
        const float* __restrict__ b, float* __restrict__ y) {
    const int bid  = blockIdx.x;            // k*54 + c
    const int k    = bid / FC1;
    const int c    = bid - k * FC1;
    const int wave = threadIdx.x >> 6;
    const int lane = threadIdx.x & 63;
    const float4* x4 = (const float4*)(x2 + (size_t)k * N * DOUT) + wave * 512 + lane;
    const float4* w4 = (const float4*)(wt + (size_t)c * N * DOUT) + wave * 512 + lane;
    float s0 = 0.f, s1 = 0.f;
    #pragma unroll
    for (int q = 0; q < 8; q += 2) {
        float4 a0 = x4[q * 64],      w0 = w4[q * 64];
        float4 a1 = x4[q * 64 + 64], w1 = w4[q * 64 + 64];
        s0 += a0.x * w0.x + a0.y * w0.y + a0.z * w0.z + a0.w * w0.w;
        s1 += a1.x * w1.x + a1.y * w1.y + a1.z * w1.z + a1.w * w1.w;
    }
    float s = s0 + s1;
    #pragma unroll
    for (int off = 32; off > 0; off >>= 1) s += __shfl_xor(s, off);
    __shared__ float red[4];
    if (lane == 0) red[wave] = s;
    __syncthreads();
    if (threadIdx.x == 0)
        y[bid] = fmaxf(red[0] + red[1] + red[2] + red[3] + b[c], 0.f);
}

// ---------------------------------------------------------------------------
// Final: out[k,n] = y[k,:] . out_w[:,n] + out_b[n].  One thread per (k,n).
// ---------------------------------------------------------------------------
__global__ void fc2_kernel(const float* __restrict__ y,
                           const float* __restrict__ out_w,
                           const float* __restrict__ out_b,
                           float* __restrict__ out) {
    int n = blockIdx.x * blockDim.x + threadIdx.x;   // 0..1023
    int k = blockIdx.y;
    const float* yk = y + (size_t)k * FC1;
    float s = out_b[n];
    #pragma unroll 6
    for (int c = 0; c < FC1; c++) s += yk[c] * out_w[(size_t)c * N + n];
    out[(size_t)k * N + n] = s;
}

// ---------------------------------------------------------------------------
extern "C" void kernel_launch(void* const* d_in, const int* in_sizes, int n_in,
                              void* d_out, int out_size, void* d_ws, size_t ws_size,
                              hipStream_t stream) {
    const float* X     = (const float*)d_in[0];
    const int*   adj   = (const int*)  d_in[1];
    const float* W1    = (const float*)d_in[2];
    const float* a1    = (const float*)d_in[3];
    const float* W2    = (const float*)d_in[4];
    const float* a2    = (const float*)d_in[5];
    const float* fc1w  = (const float*)d_in[6];
    const float* fc1b  = (const float*)d_in[7];
    const float* outw  = (const float*)d_in[8];
    const float* outb  = (const float*)d_in[9];
    float* out = (float*)d_out;

    // Workspace layout (floats); ~8.05 MB total
    float* ws  = (float*)d_ws;
    float* h1  = ws;                       // 262144
    float* f11 = h1  + 262144;             // 65536
    float* f21 = f11 + 65536;              // 65536
    float* h2  = f21 + 65536;              // 524288
    float* f12 = h2  + 524288;             // 65536
    float* f22 = f12 + 65536;              // 65536
    float* x2  = f22 + 65536;              // 524288
    float* y   = x2  + 524288;             // 4096 (3456 used)
    float* wt  = y   + 4096;               // 442368
    unsigned long long* mT = (unsigned long long*)(wt + 442368);  // 16384 u64

    // 1) fused prep: mask pack (transposed) + fc1_w transpose + gat1 proj
    prep_kernel<<<dim3(2240), dim3(512), 0, stream>>>(
        adj, mT, fc1w, wt, X, W1, a1, h1, f11, f21);

    // 2) layer-1 attention (global-broadcast), fused with layer-2 projection
    gat_attn7<4, true><<<dim3(512), dim3(512), 0, stream>>>(
        mT, h1, f11, f21, W2, a2, h2, f12, f22);

    // 3) layer-2 attention (global-broadcast)
    gat_attn7<8, false><<<dim3(512), dim3(512), 0, stream>>>(
        mT, h2, f12, f22, nullptr, nullptr, x2, nullptr, nullptr);

    // 4) FC head
    fc1_kernel<<<dim3(K * FC1), dim3(256), 0, stream>>>(x2, wt, fc1b, y);
    fc2_kernel<<<dim3(N / 256, K), dim3(256), 0, stream>>>(y, outw, outb, out);
}

// Round 8
// 156.628 us; speedup vs baseline: 1.4157x; 1.0430x over previous
//
#include <hip/hip_runtime.h>

// Problem constants (from reference setup_inputs)
constexpr int K    = 64;
constexpr int N    = 1024;
constexpr int DIN  = 16;
constexpr int H1   = 4;
constexpr int DOUT = 8;
constexpr int FC1  = 54;

#define ALPHA_F   (0.01f)
#define LOG2E_F   (1.4426950408889634f)

__device__ inline float fast_exp2(float x) {
#if __has_builtin(__builtin_amdgcn_exp2f)
    return __builtin_amdgcn_exp2f(x);      // raw v_exp_f32
#else
    return __expf(x * 0.6931471805599453f);
#endif
}

// ---------------------------------------------------------------------------
// prep kernel: three independent jobs split by blockIdx range.
//  A) blocks [0,2048):    maskT[jw*N+i] = ballot bits of adj[i][jw*64+lane]
//  B) blocks [2048,2112): LDS-tile transpose fc1_w [8192,54] -> wt [54,8192]
//  C) blocks [2112,2240): gat1 projection: h1 = X@W1; f11/f21 logits *log2e
// ---------------------------------------------------------------------------
__global__ __launch_bounds__(512) void prep_kernel(
        const int* __restrict__ adj, unsigned long long* __restrict__ maskT,
        const float* __restrict__ fc1w, float* __restrict__ wt,
        const float* __restrict__ X, const float* __restrict__ W1,
        const float* __restrict__ a1,
        float* __restrict__ h1, float* __restrict__ f11, float* __restrict__ f21) {
    int b = blockIdx.x;
    if (b < 2048) {
        int wave = threadIdx.x >> 6, lane = threadIdx.x & 63;
        int wid = b * 8 + wave;            // 0..16383
        int jw  = wid >> 10;               // 0..15
        int i   = wid & 1023;
        int v = adj[i * N + (jw << 6) + lane];        // coalesced 256B/wave
        unsigned long long m = __ballot(v > 0);       // bit lane = adj>0
        if (lane == 0) maskT[jw * N + i] = m;
    } else if (b < 2112) {
        // transpose 128-row tile: coalesced read + coalesced write via LDS
        __shared__ float tile[128 * FC1];
        const int m0 = (b - 2048) * 128;
        const float* src = fc1w + (size_t)m0 * FC1;
        for (int idx = threadIdx.x; idx < 128 * FC1; idx += 512)
            tile[idx] = src[idx];                     // consecutive
        __syncthreads();
        for (int idx = threadIdx.x; idx < 128 * FC1; idx += 512) {
            int c = idx >> 7, mm = idx & 127;
            wt[(size_t)c * (N * DOUT) + m0 + mm] = tile[mm * FC1 + c];
        }
    } else {
        int idx = (b - 2112) * 512 + threadIdx.x;     // < 65536 : k*N+n
        const float4* x4 = (const float4*)(X + (size_t)idx * DIN);
        float h[H1] = {0.f, 0.f, 0.f, 0.f};
        #pragma unroll
        for (int q = 0; q < 4; q++) {
            float4 xv = x4[q];
            #pragma unroll
            for (int f = 0; f < H1; f++) {
                h[f] += xv.x * W1[(q * 4 + 0) * H1 + f] + xv.y * W1[(q * 4 + 1) * H1 + f]
                      + xv.z * W1[(q * 4 + 2) * H1 + f] + xv.w * W1[(q * 4 + 3) * H1 + f];
            }
        }
        float s1 = 0.f, s2 = 0.f;
        #pragma unroll
        for (int f = 0; f < H1; f++) { s1 += h[f] * a1[f]; s2 += h[f] * a1[H1 + f]; }
        *(float4*)(h1 + (size_t)idx * H1) = make_float4(h[0], h[1], h[2], h[3]);
        f11[idx] = s1 * LOG2E_F;           // pre-scaled for exp2
        f21[idx] = s2 * LOG2E_F;
    }
}

// ---------------------------------------------------------------------------
// Attention v8: per-j broadcast operands via the SCALAR (SMEM) path.
// Block = 256 thr (4 waves), 64 rows (1 row per lane, zero redundancy);
// waves split j 4 x 256.  The wave id is materialized with readfirstlane so
// the j-chunk base is SGPR-resident -> f2[j] / h[j][:] addresses are provably
// wave-uniform affine -> compiler emits s_load (batched dwordx4/x8/x16 on
// the lgkmcnt path), leaving VMEM (only the 4 per-lane mask words) and VALU
// free.  v_fma takes one SGPR operand directly.  LDS only for the tiny
// [4][64][F+1] partial combine.  Grid 1024 -> 4 blocks/CU, 4 waves/SIMD.
// Softmax without max-subtract (logits pre-scaled by log2e -> raw exp2;
// mask zeroes p after exp -> exact).  FUSE: layer-2 projection in epilogue.
// ---------------------------------------------------------------------------
template <int F, bool FUSE>
__global__ __launch_bounds__(256, 4) void gat_attn8(
        const unsigned long long* __restrict__ maskT,  // [16][N]
        const float* __restrict__ h,    // [K,N,F]
        const float* __restrict__ f1,   // [K,N]  (x log2e)
        const float* __restrict__ f2,   // [K,N]  (x log2e)
        const float* __restrict__ W2,   // [4,8]  (FUSE only)
        const float* __restrict__ a2,   // [16]   (FUSE only)
        float* __restrict__ o_x,        // FUSE: h2 [K,N,8]; else out [K,N,F]
        float* __restrict__ o_f1,       // FUSE: f12 (x log2e)
        float* __restrict__ o_f2) {     // FUSE: f22 (x log2e)
    __shared__ float part[4 * 64 * (F + 1)];     // [wave][row][F+1]

    const int tid  = threadIdx.x;
    const int lane = tid & 63;
    const int wv   = __builtin_amdgcn_readfirstlane(tid >> 6);  // SGPR wave id
    const int k    = blockIdx.x >> 4;            // 16 blocks per k
    const int iset = blockIdx.x & 15;
    const int i    = iset * 64 + lane;

    const float  f1i = f1[k * N + i];
    const float* f2k = f2 + k * N;               // uniform base
    const float* hk  = h + (size_t)k * N * F;    // uniform base

    float s = 0.f;
    float acc[F];
    #pragma unroll
    for (int f = 0; f < F; f++) acc[f] = 0.f;

    const int j0 = wv * 256;                     // SGPR chunk base
    #pragma unroll
    for (int w = 0; w < 4; w++) {                // 4 mask words of 64 j
        const int jb = j0 + w * 64;
        const unsigned long long mw = maskT[(jb >> 6) * N + i];  // per-lane VMEM
        #pragma unroll
        for (int half = 0; half < 2; half++) {
            const unsigned wb = half ? (unsigned)(mw >> 32) : (unsigned)mw;
            const int jh = jb + half * 32;
            #pragma unroll 8
            for (int t = 0; t < 32; t++) {
                const int j = jh + t;            // uniform
                const float f2j = f2k[j];        // s_load
                const float* hj = hk + (size_t)j * F;   // uniform
                float y = f1i + f2j;
                float e = fmaxf(y, ALPHA_F * y); // leaky (pre-scaled by log2e)
                float p = fast_exp2(e);
                p = (wb & (1u << t)) ? p : 0.f;  // mask -> exact 0
                s += p;
                #pragma unroll
                for (int f = 0; f < F; f++) acc[f] += p * hj[f];  // sgpr operand
            }
        }
    }

    // per-wave partials (stride F+1 odd)
    {
        float* pp = part + (wv * 64 + lane) * (F + 1);
        pp[0] = s;
        #pragma unroll
        for (int f = 0; f < F; f++) pp[1 + f] = acc[f];
    }
    __syncthreads();

    if (tid < 64) {
        const int r = tid;
        float st = 0.f;
        float at[F];
        #pragma unroll
        for (int f = 0; f < F; f++) at[f] = 0.f;
        #pragma unroll
        for (int w = 0; w < 4; w++) {
            const float* pp = part + (w * 64 + r) * (F + 1);
            st += pp[0];
            #pragma unroll
            for (int f = 0; f < F; f++) at[f] += pp[1 + f];
        }
        const float inv = (st > 0.f) ? 1.f / st : 0.f;
        const int orow = k * N + iset * 64 + r;
        float xo[F];
        #pragma unroll
        for (int f = 0; f < F; f++) xo[f] = fmaxf(at[f] * inv, 0.f);  // relu

        if constexpr (FUSE) {
            // layer-2 projection: h2 = xo(4) @ W2(4x8); logits vs a2 (x log2e)
            float hv[DOUT];
            #pragma unroll
            for (int f = 0; f < DOUT; f++) {
                hv[f] = xo[0] * W2[f]      + xo[1] * W2[8 + f]
                      + xo[2] * W2[16 + f] + xo[3] * W2[24 + f];
            }
            float t1 = 0.f, t2 = 0.f;
            #pragma unroll
            for (int f = 0; f < DOUT; f++) { t1 += hv[f] * a2[f]; t2 += hv[f] * a2[DOUT + f]; }
            float* op = o_x + (size_t)orow * DOUT;
            *(float4*)op       = make_float4(hv[0], hv[1], hv[2], hv[3]);
            *(float4*)(op + 4) = make_float4(hv[4], hv[5], hv[6], hv[7]);
            o_f1[orow] = t1 * LOG2E_F;
            o_f2[orow] = t2 * LOG2E_F;
        } else {
            float* op = o_x + (size_t)orow * F;
            *(float4*)op = make_float4(xo[0], xo[1], xo[2], xo[3]);
            if (F == 8)
                *(float4*)(op + 4) = make_float4(xo[4], xo[5], xo[6], xo[7]);
        }
    }
}

// ---------------------------------------------------------------------------
// FC1: y[k,c] = relu( x2[k,:] . wt[c,:] + b[c] ).
// One 256-thread block per (k,c): 4 waves split the 8192-dim, 2 accumulator
// chains per wave, butterfly + LDS combine.
// ---------------------------------------------------------------------------
__global__ __launch_bounds__(256) void fc1_kernel(
        const float* __restrict__ x2, const float* __restrict__ wt,
        const float* __restrict__ b, float* __restrict__ y) {
    const int bid  = blockIdx.x;            // k*54 + c
    const int k    = bid / FC1;
    const int c    = bid - k * FC1;
    const int wave = threadIdx.x >> 6;
    const int lane = threadIdx.x & 63;
    const float4* x4 = (const float4*)(x2 + (size_t)k * N * DOUT) + wave * 512 + lane;
    const float4* w4 = (const float4*)(wt + (size_t)c * N * DOUT) + wave * 512 + lane;
    float s0 = 0.f, s1 = 0.f;
    #pragma unroll
    for (int q = 0; q < 8; q += 2) {
        float4 a0 = x4[q * 64],      w0 = w4[q * 64];
        float4 a1 = x4[q * 64 + 64], w1 = w4[q * 64 + 64];
        s0 += a0.x * w0.x + a0.y * w0.y + a0.z * w0.z + a0.w * w0.w;
        s1 += a1.x * w1.x + a1.y * w1.y + a1.z * w1.z + a1.w * w1.w;
    }
    float s = s0 + s1;
    #pragma unroll
    for (int off = 32; off > 0; off >>= 1) s += __shfl_xor(s, off);
    __shared__ float red[4];
    if (lane == 0) red[wave] = s;
    __syncthreads();
    if (threadIdx.x == 0)
        y[bid] = fmaxf(red[0] + red[1] + red[2] + red[3] + b[c], 0.f);
}

// ---------------------------------------------------------------------------
// Final: out[k,n] = y[k,:] . out_w[:,n] + out_b[n].  One thread per (k,n).
// ---------------------------------------------------------------------------
__global__ void fc2_kernel(const float* __restrict__ y,
                           const float* __restrict__ out_w,
                           const float* __restrict__ out_b,
                           float* __restrict__ out) {
    int n = blockIdx.x * blockDim.x + threadIdx.x;   // 0..1023
    int k = blockIdx.y;
    const float* yk = y + (size_t)k * FC1;
    float s = out_b[n];
    #pragma unroll 6
    for (int c = 0; c < FC1; c++) s += yk[c] * out_w[(size_t)c * N + n];
    out[(size_t)k * N + n] = s;
}

// ---------------------------------------------------------------------------
extern "C" void kernel_launch(void* const* d_in, const int* in_sizes, int n_in,
                              void* d_out, int out_size, void* d_ws, size_t ws_size,
                              hipStream_t stream) {
    const float* X     = (const float*)d_in[0];
    const int*   adj   = (const int*)  d_in[1];
    const float* W1    = (const float*)d_in[2];
    const float* a1    = (const float*)d_in[3];
    const float* W2    = (const float*)d_in[4];
    const float* a2    = (const float*)d_in[5];
    const float* fc1w  = (const float*)d_in[6];
    const float* fc1b  = (const float*)d_in[7];
    const float* outw  = (const float*)d_in[8];
    const float* outb  = (const float*)d_in[9];
    float* out = (float*)d_out;

    // Workspace layout (floats); ~8.05 MB total
    float* ws  = (float*)d_ws;
    float* h1  = ws;                       // 262144
    float* f11 = h1  + 262144;             // 65536
    float* f21 = f11 + 65536;              // 65536
    float* h2  = f21 + 65536;              // 524288
    float* f12 = h2  + 524288;             // 65536
    float* f22 = f12 + 65536;              // 65536
    float* x2  = f22 + 65536;              // 524288
    float* y   = x2  + 524288;             // 4096 (3456 used)
    float* wt  = y   + 4096;               // 442368
    unsigned long long* mT = (unsigned long long*)(wt + 442368);  // 16384 u64

    // 1) fused prep: mask pack (transposed) + fc1_w transpose + gat1 proj
    prep_kernel<<<dim3(2240), dim3(512), 0, stream>>>(
        adj, mT, fc1w, wt, X, W1, a1, h1, f11, f21);

    // 2) layer-1 attention (SMEM-broadcast), fused with layer-2 projection
    gat_attn8<4, true><<<dim3(K * 16), dim3(256), 0, stream>>>(
        mT, h1, f11, f21, W2, a2, h2, f12, f22);

    // 3) layer-2 attention (SMEM-broadcast)
    gat_attn8<8, false><<<dim3(K * 16), dim3(256), 0, stream>>>(
        mT, h2, f12, f22, nullptr, nullptr, x2, nullptr, nullptr);

    // 4) FC head
    fc1_kernel<<<dim3(K * FC1), dim3(256), 0, stream>>>(x2, wt, fc1b, y);
    fc2_kernel<<<dim3(N / 256, K), dim3(256), 0, stream>>>(y, outw, outb, out);
}